// Round 16
// baseline (902.237 us; speedup 1.0000x reference)
//
#include <hip/hip_runtime.h>
#include <hip/hip_fp16.h>
#include <hip/hip_bf16.h>
#include <cstdint>

#define TLEN  256
#define HD    128
#define BATCH 8
#define VOCAB 32000
#define EMBD  32
#define ROWB  272   // 256B row + 16B pad
#define NWORK 240   // worker blocks (grid = 8 + NWORK)

typedef __attribute__((ext_vector_type(8))) short short8v;
typedef __attribute__((ext_vector_type(8))) unsigned short ushort8v;
typedef __attribute__((ext_vector_type(4))) float f32x4;
typedef __attribute__((ext_vector_type(2))) float f32x2;
typedef __attribute__((ext_vector_type(2))) _Float16 hv2;

__device__ __forceinline__ float tanhfast(float x){
  float e = __builtin_amdgcn_exp2f(x * 2.8853900817779268f);
  return 1.0f - 2.0f * __builtin_amdgcn_rcpf(e + 1.0f);
}
__device__ __forceinline__ unsigned short f2bf(float f){
  unsigned u = __float_as_uint(f);
  return (unsigned short)((u + 0x7fffu + ((u >> 16) & 1u)) >> 16);
}
__device__ __forceinline__ float h2f(unsigned short u){
  return __half2float(__ushort_as_half(u));
}
__device__ __forceinline__ unsigned short f2h(float f){
  return __half_as_ushort(__float2half(f));
}
__device__ __forceinline__ unsigned pk2(float lo, float hi){
  return __builtin_bit_cast(unsigned, __floats2half2_rn(lo, hi));
}
__device__ __forceinline__ float fdot2u(unsigned a, unsigned b, float c){
#if __has_builtin(__builtin_amdgcn_fdot2)
  return __builtin_amdgcn_fdot2(__builtin_bit_cast(hv2, a), __builtin_bit_cast(hv2, b), c, false);
#else
  float2 fa = __half22float2(__builtin_bit_cast(__half2, a));
  float2 fb = __half22float2(__builtin_bit_cast(__half2, b));
  return c + fa.x*fb.x + fa.y*fb.y;
#endif
}
__device__ __forceinline__ f32x2 fma2(f32x2 a, f32x2 b, f32x2 c){
#if __has_builtin(__builtin_elementwise_fma)
  return __builtin_elementwise_fma(a, b, c);
#else
  f32x2 r; r.x = fmaf(a.x, b.x, c.x); r.y = fmaf(a.y, b.y, c.y); return r;
#endif
}
__device__ __forceinline__ void ld8u(const void* p, unsigned* d){
  uint4 a = *(const uint4*)p;
  uint4 b = *(const uint4*)((const char*)p + 16);
  d[0]=a.x; d[1]=a.y; d[2]=a.z; d[3]=a.w; d[4]=b.x; d[5]=b.y; d[6]=b.z; d[7]=b.w;
}
__device__ __forceinline__ void gload_lds16(const void* g, void* l){
  __builtin_amdgcn_global_load_lds((const __attribute__((address_space(1))) void*)g,
                                   (__attribute__((address_space(3))) void*)l, 16, 0, 0);
}

// ---- cross-lane adds ----
__device__ __forceinline__ float dpp_add1(float x){
  int y = __builtin_amdgcn_mov_dpp(__float_as_int(x), 0xB1, 0xF, 0xF, true);
  return x + __int_as_float(y);
}
__device__ __forceinline__ float dpp_add2(float x){
  int y = __builtin_amdgcn_mov_dpp(__float_as_int(x), 0x4E, 0xF, 0xF, true);
  return x + __int_as_float(y);
}
__device__ __forceinline__ float dpp_shl4(float x){   // valid (l&15)<12
  int y = __builtin_amdgcn_mov_dpp(__float_as_int(x), 0x104, 0xF, 0xF, true);
  return x + __int_as_float(y);
}
__device__ __forceinline__ float dpp_shl8(float x){   // valid (l&15)<8
  int y = __builtin_amdgcn_mov_dpp(__float_as_int(x), 0x108, 0xF, 0xF, true);
  return x + __int_as_float(y);
}
__device__ __forceinline__ float swz_add4(float x){
  int y = __builtin_amdgcn_ds_swizzle(__float_as_int(x), 0x101F);
  return x + __int_as_float(y);
}
__device__ __forceinline__ float swz_add16(float x){
  int y = __builtin_amdgcn_ds_swizzle(__float_as_int(x), 0x401F);
  return x + __int_as_float(y);
}

// interleaved score slot: stripe-contiguous for P3
#define SCR(s) ((((s) & 15) << 4) | ((s) >> 4))

// ---------------- prep 1 (+ progress reset) ----------------
__global__ void prep_ex_kernel(const int* __restrict__ x, const float* __restrict__ emb,
                               const float* __restrict__ W_ih, const float* __restrict__ b_ih,
                               const float* __restrict__ b_hh, float* __restrict__ ex,
                               int* progress){
  int bt = blockIdx.x;
  int c  = threadIdx.x;
  if (bt == 0 && c < BATCH) progress[c] = -1;
  int ix = x[bt];
  const float* er = emb + (long)ix * EMBD;
  float acc = b_ih[c] + b_hh[c];
  #pragma unroll
  for (int e = 0; e < EMBD; ++e) acc += er[e] * W_ih[e * HD + c];
  ex[bt * HD + c] = acc;
}

// ---------------- prep 2 ----------------
__global__ void prep_wt_kernel(const float* __restrict__ W_out, unsigned short* __restrict__ Wbt){
  __shared__ float tile[32][33];
  int tx = threadIdx.x & 31, ty = threadIdx.x >> 5;
  int n0 = blockIdx.x * 32, k0 = blockIdx.y * 32;
  #pragma unroll
  for (int j = 0; j < 4; ++j){
    int k = ty + j * 8;
    tile[k][tx] = W_out[(long)(k0 + k) * VOCAB + n0 + tx];
  }
  __syncthreads();
  #pragma unroll
  for (int j = 0; j < 4; ++j){
    int n = ty + j * 8;
    Wbt[(long)(n0 + n) * HD + k0 + tx] = f2bf(tile[tx][n]);
  }
}

// ---------------- scan role (r13 body + progress publish) ----------------
__device__ void scan_body(char* lds,
                          const float* W_attn, const float* U_attn, const float* v_attn,
                          const float* W_ih, const float* W_hh, const float* ex,
                          unsigned short* out_bf, float* h_final, int* progress,
                          int b, int tid){
  char* keysB = lds;                       // 256*272 = 69632 B (G = e^{2k}, fp16)
  char* hWcB  = lds + 69632;               // 69632 B (h@Wc, fp16) -- zero-backed
  float* fbuf   = (float*)(lds + 139264);
  float* E_pad    = fbuf;                  // 160: e^{2q}
  float* hh_lds   = fbuf + 160;            // 128
  float* scores_e = fbuf + 288;            // 256 (interleaved SCR layout, zero-backed)
  unsigned* h_pk  = (unsigned*)(fbuf + 544); // 64

  const int lane = tid & 63, wv = tid >> 6;
  const int c_   = tid >> 3, rg = tid & 7;
  const int sg   = lane >> 3, cg = lane & 7;
  const int cg3  = cg & 3;
  const int sgx  = sg + 8*(cg >> 2);            // 0..15 stripe (P3)
  const int cp   = wv*4 + cg3;                  // col pair -> cols 2cp,2cp+1

  const float LOG2E = 1.4426950408889634f;
  const float C2F   = 2.8853900817779268f;

  if (tid < HD) hh_lds[tid] = 0.f;

  // ---- stage weights into packed-fp16 VGPRs ----
  unsigned Wa2[8], Ua2[8], Wh2[8], Wc2[8];
  {
    float* stage = (float*)lds;
    float4* d4 = (float4*)stage;
    {
      const float4* s4 = (const float4*)W_attn;
      for (int i = 0; i < 4; ++i) d4[tid + i*1024] = s4[tid + i*1024];
      __syncthreads();
      #pragma unroll
      for (int i = 0; i < 8; ++i)
        Wa2[i] = pk2(stage[(rg*16 + 2*i)*HD + c_], stage[(rg*16 + 2*i + 1)*HD + c_]);
      __syncthreads();
    }
    {
      const float4* s4 = (const float4*)U_attn;
      for (int i = 0; i < 4; ++i) d4[tid + i*1024] = s4[tid + i*1024];
      __syncthreads();
      #pragma unroll
      for (int i = 0; i < 8; ++i)
        Ua2[i] = pk2(stage[(rg*16 + 2*i)*HD + c_], stage[(rg*16 + 2*i + 1)*HD + c_]);
      __syncthreads();
    }
    {
      const float4* s4 = (const float4*)W_hh;
      for (int i = 0; i < 4; ++i) d4[tid + i*1024] = s4[tid + i*1024];
      __syncthreads();
      #pragma unroll
      for (int i = 0; i < 8; ++i)
        Wh2[i] = pk2(stage[(rg*16 + 2*i)*HD + c_], stage[(rg*16 + 2*i + 1)*HD + c_]);
      __syncthreads();
    }
    {
      const float4* s4 = (const float4*)(W_ih + EMBD*HD);
      for (int i = 0; i < 4; ++i) d4[tid + i*1024] = s4[tid + i*1024];
      __syncthreads();
      #pragma unroll
      for (int i = 0; i < 8; ++i)
        Wc2[i] = pk2(stage[(rg*16 + 2*i)*HD + c_], stage[(rg*16 + 2*i + 1)*HD + c_]);
      __syncthreads();
    }
  }

  // ---- zero-back hWcB + scores_e + h_pk ----
  {
    float4 z = {0.f, 0.f, 0.f, 0.f};
    float4* hz = (float4*)hWcB;
    hz[tid] = z; hz[tid + 1024] = z; hz[tid + 2048] = z; hz[tid + 3072] = z;
    if (tid < 256) hz[tid + 4096] = z;
    if (tid < 64) ((float4*)scores_e)[tid] = z;
    if (tid < 64) h_pk[tid] = 0u;
  }

  // ---- v in registers (cols cg*16..+15) as f32x2 + FULL 128-sum ----
  f32x2 v2[8]; float VsumL;
  {
    const float* vg = v_attn + cg*16;
    float s = 0.f;
    #pragma unroll
    for (int i = 0; i < 8; ++i){
      f32x2 vv; vv.x = vg[2*i]; vv.y = vg[2*i+1];
      v2[i] = vv; s += vv.x + vv.y;
    }
    s = dpp_add1(s); s = dpp_add2(s); s = swz_add4(s);
    VsumL = s * LOG2E;
  }

  const float* exb = ex + (long)b * TLEN * HD;

  for (int t = 0; t < TLEN; ++t){
    float2 evpre = *(const float2*)(exb + t*HD + 2*cp);   // prefetch for P3 tail

    if (t > 0){
      // ---- P1: 4 packed GEMVs of h ----
      {
        unsigned h2u[8];
        ld8u((const char*)h_pk + rg*32, h2u);
        float aq = 0.f, ak = 0.f, ah = 0.f, aw = 0.f;
        #pragma unroll
        for (int i = 0; i < 8; ++i){
          aq = fdot2u(h2u[i], Wa2[i], aq);
          ak = fdot2u(h2u[i], Ua2[i], ak);
          ah = fdot2u(h2u[i], Wh2[i], ah);
          aw = fdot2u(h2u[i], Wc2[i], aw);
        }
        aq = dpp_add1(aq); aq = dpp_add2(aq); aq = dpp_shl4(aq);
        ak = dpp_add1(ak); ak = dpp_add2(ak); ak = dpp_shl4(ak);
        ah = dpp_add1(ah); ah = dpp_add2(ah); ah = dpp_shl4(ah);
        aw = dpp_add1(aw); aw = dpp_add2(aw); aw = dpp_shl4(aw);
        if (rg == 0){
          E_pad[c_ + (c_>>4)*4] = __builtin_amdgcn_exp2f(aq * C2F);      // e^{2q}
          hh_lds[c_] = ah;
          int s = t - 1;
          float G = fminf(__builtin_amdgcn_exp2f(ak * C2F), 60000.f);    // e^{2k}
          *(unsigned short*)(keysB + s*ROWB + c_*2) = f2h(G);
          *(unsigned short*)(hWcB  + s*ROWB + c_*2) = f2h(aw);
        }
      }
      __syncthreads();  // S1

      // ---- P2: e_s = exp(v . tanh(q+k_s)); tanh = 1 - 2/(1+E*G) ----
      {
        f32x2 E2[8];
        {
          const float4* E4 = (const float4*)(E_pad + cg*20);
          #pragma unroll
          for (int i = 0; i < 4; ++i){
            float4 ev = E4[i];
            f32x2 a, bb; a.x = ev.x; a.y = ev.y; bb.x = ev.z; bb.y = ev.w;
            E2[2*i] = a; E2[2*i+1] = bb;
          }
        }
        #pragma unroll
        for (int it = 0; it < 2; ++it){
          int s = wv*8 + sg + it*128;
          if (s < t){
            unsigned gu[8];
            ld8u(keysB + s*ROWB + cg*32, gu);
            f32x2 D[8];
            #pragma unroll
            for (int i = 0; i < 8; ++i){
              hv2 g = __builtin_bit_cast(hv2, gu[i]);
              f32x2 d;
              d.x = fmaf((float)g.x, E2[i].x, 1.0f);
              d.y = fmaf((float)g.y, E2[i].y, 1.0f);
              D[i] = d;
            }
            f32x2 acc2; acc2.x = 0.f; acc2.y = 0.f;
            #pragma unroll
            for (int i = 0; i < 8; i += 2){
              f32x2 p = D[i] * D[i+1];
              float R = __builtin_amdgcn_rcpf(p.x * p.y);
              f32x2 sw = p.yx * R;
              acc2 = fma2(v2[i],   sw * D[i+1], acc2);
              acc2 = fma2(v2[i+1], sw * D[i],   acc2);
            }
            float ac = acc2.x + acc2.y;
            ac = dpp_add1(ac); ac = dpp_add2(ac); ac = dpp_shl4(ac);   // cg-reduce
            float e = __builtin_amdgcn_exp2f(fmaf(-C2F, ac, VsumL));
            if (cg == 0) scores_e[SCR(s)] = e;
          }
        }
      }
      __syncthreads();  // S2
    }

    // ---- P3: ctxWc = (sum_s e_s * hWc[s]) / (sum_s e_s), then h_new inline ----
    {
      float a0 = 0.f, a1 = 0.f, es = 0.f;
      const char* pw = hWcB + cp*4 + sgx*ROWB;
      const float* sc = scores_e + sgx*16;
      int jmax = (t - sgx + 15) >> 4;                  // #valid stripe slots (<=16)
      for (int j = 0; j < jmax; j += 4){
        float4 e4 = *(const float4*)(sc + j);          // 4 scores, zero-backed
        hv2 h0 = __builtin_bit_cast(hv2, *(const unsigned*)(pw));
        hv2 h1 = __builtin_bit_cast(hv2, *(const unsigned*)(pw + 16*ROWB));
        hv2 h2v = __builtin_bit_cast(hv2, *(const unsigned*)(pw + 32*ROWB));
        hv2 h3 = __builtin_bit_cast(hv2, *(const unsigned*)(pw + 48*ROWB));
        es += (e4.x + e4.y) + (e4.z + e4.w);
        a0 = fmaf((float)h0.x, e4.x, a0); a1 = fmaf((float)h0.y, e4.x, a1);
        a0 = fmaf((float)h1.x, e4.y, a0); a1 = fmaf((float)h1.y, e4.y, a1);
        a0 = fmaf((float)h2v.x, e4.z, a0); a1 = fmaf((float)h2v.y, e4.z, a1);
        a0 = fmaf((float)h3.x, e4.w, a0); a1 = fmaf((float)h3.y, e4.w, a1);
        pw += 64*ROWB;
      }
      a0 = dpp_shl4(a0); a0 = dpp_shl8(a0); a0 = swz_add16(a0); a0 += __shfl_xor(a0, 32);
      a1 = dpp_shl4(a1); a1 = dpp_shl8(a1); a1 = swz_add16(a1); a1 += __shfl_xor(a1, 32);
      es = dpp_shl4(es); es = dpp_shl8(es); es = swz_add16(es); es += __shfl_xor(es, 32);
      if (sgx == 0){
        float invZ = __builtin_amdgcn_rcpf(es);        // es>0 for t>0; t=0 selected away
        float cw0 = (t > 0) ? a0 * invZ : 0.f;
        float cw1 = (t > 0) ? a1 * invZ : 0.f;
        int c0 = 2*cp;
        float2 hhv = *(const float2*)(&hh_lds[c0]);
        float h0 = tanhfast(evpre.x + hhv.x + cw0);
        float h1 = tanhfast(evpre.y + hhv.y + cw1);
        h_pk[cp] = pk2(h0, h1);
        unsigned po = (unsigned)f2bf(h0) | ((unsigned)f2bf(h1) << 16);
        *(unsigned*)(&out_bf[((long)b*TLEN + t)*HD + c0]) = po;
        if (t == TLEN-1){ float2 hw = { h0, h1 }; *(float2*)&h_final[b*HD + c0] = hw; }
      }
    }
    __syncthreads();  // S3

    // ---- publish progress (visible cross-XCD) at t = 63,127,191,255 ----
    if (((t & 63) == 63) && tid == 0){
      __threadfence();
      __hip_atomic_store(&progress[b], t, __ATOMIC_RELEASE, __HIP_MEMORY_SCOPE_AGENT);
    }
  }
}

// ---------------- worker role: LDS-resident B, barrier-free per-wave strips ----------------
// Block w stages n-tile(s) {w, 240+w} into LDS once (no wait needed), then each of
// its 16 waves independently processes strips: wave v, batch bb -> slot (v+4bb)&15,
// strip = bb*16+slot. 2 strips per unlock-phase per wave (balanced tail).
__device__ void worker_body(char* lds, const unsigned short* A, const unsigned short* Bt,
                            const float* bias, float* C, int* progress, int wid, int tid){
  const int lane = tid & 63, wv = tid >> 6;
  const int r15 = lane & 15, r4 = lane >> 4;
  const int ntiles = (wid < 10) ? 2 : 1;

  // ---- stage B tiles: linear LDS dest, pre-swizzled global source (rule 21) ----
  for (int ti = 0; ti < ntiles; ++ti){
    int ni = (ti == 0) ? wid : (240 + wid);
    const char* Bb = (const char*)Bt + (long)ni * 32768;
    #pragma unroll
    for (int it = 0; it < 2; ++it){
      int p  = it*16384 + tid*16;
      int ps = p ^ (((p >> 8) & 7) << 4);
      gload_lds16(Bb + ps, lds + ti*32768 + p);
    }
  }
  __syncthreads();   // staging drained; only barrier in worker path

  for (int ti = 0; ti < ntiles; ++ti){
    int ni = (ti == 0) ? wid : (240 + wid);
    const char* sB = lds + ti*32768;
    for (int p = 0; p < 4; ++p){
      int need = p*64 + 63;
      for (int bb = 0; bb < 8; ++bb){
        int slot = (wv + 4*bb) & 15;
        if ((slot >> 2) != p) continue;
        int strip = bb*16 + slot;

        while (__hip_atomic_load(&progress[bb], __ATOMIC_ACQUIRE, __HIP_MEMORY_SCOPE_AGENT) < need)
          __builtin_amdgcn_s_sleep(16);

        const char* Ab = (const char*)A + (long)strip * 4096;   // 16 rows x 256 B
        f32x4 acc[8] = {};
        #pragma unroll
        for (int kk = 0; kk < 4; ++kk){
          short8v af = *(const short8v*)(Ab + r15*256 + kk*64 + r4*16);
          #pragma unroll
          for (int n2 = 0; n2 < 8; ++n2){
            int row = n2*16 + r15;
            int off = row*256 + kk*64 + r4*16;
            short8v bf = *(const short8v*)(sB + (off ^ ((row & 7) << 4)));
            acc[n2] = __builtin_amdgcn_mfma_f32_16x16x32_bf16(af, bf, acc[n2], 0, 0, 0);
          }
        }
        int rbase = strip*16 + r4*4;
        #pragma unroll
        for (int n2 = 0; n2 < 8; ++n2){
          int col = ni*128 + n2*16 + r15;
          float bv = bias[col];
          #pragma unroll
          for (int j = 0; j < 4; ++j)
            C[(long)(rbase + j) * VOCAB + col] = acc[n2][j] + bv;
        }
      }
    }
  }
}

// ---------------- fused: scan blocks (0..7) + GEMM workers (8..247) ----------------
__launch_bounds__(1024)
__global__ void fused_kernel(const float* W_attn, const float* U_attn, const float* v_attn,
                             const float* W_ih, const float* W_hh, const float* ex,
                             unsigned short* out_bf, float* h_final,
                             const unsigned short* Bt, const float* bias, float* C,
                             int* progress){
  extern __shared__ char lds[];
  if (blockIdx.x < BATCH){
    scan_body(lds, W_attn, U_attn, v_attn, W_ih, W_hh, ex, out_bf, h_final, progress,
              blockIdx.x, threadIdx.x);
  } else {
    worker_body(lds, out_bf, Bt, bias, C, progress, blockIdx.x - BATCH, threadIdx.x);
  }
}

extern "C" void kernel_launch(void* const* d_in, const int* in_sizes, int n_in,
                              void* d_out, int out_size, void* d_ws, size_t ws_size,
                              hipStream_t stream){
  const int*   x      = (const int*)d_in[0];
  const float* emb    = (const float*)d_in[1];
  const float* W_attn = (const float*)d_in[2];
  const float* U_attn = (const float*)d_in[3];
  const float* v_attn = (const float*)d_in[4];
  const float* W_ih   = (const float*)d_in[5];
  const float* b_ih   = (const float*)d_in[6];
  const float* W_hh   = (const float*)d_in[7];
  const float* b_hh   = (const float*)d_in[8];
  const float* W_out  = (const float*)d_in[9];
  const float* b_out  = (const float*)d_in[10];

  float* logits  = (float*)d_out;
  float* h_final = logits + (long)BATCH * TLEN * VOCAB;

  char* ws = (char*)d_ws;
  float*          ex   = (float*)ws;                                // 1,048,576 B
  unsigned short* Wbt  = (unsigned short*)(ws + 1048576);           // 8,192,000 B
  unsigned short* outb = (unsigned short*)(ws + 1048576 + 8192000); // 524,288 B
  int*            progress = (int*)(ws + 1048576 + 8192000 + 524288); // 32 B

  prep_ex_kernel<<<BATCH*TLEN, HD, 0, stream>>>(x, emb, W_ih, b_ih, b_hh, ex, progress);
  prep_wt_kernel<<<dim3(VOCAB/32, HD/32), 256, 0, stream>>>(W_out, Wbt);

  const int ldsBytes = 139264 + 608*4;   // 141,696 B (scan layout; workers use first 64 KB)
  hipFuncSetAttribute((const void*)fused_kernel, hipFuncAttributeMaxDynamicSharedMemorySize, ldsBytes);
  fused_kernel<<<BATCH + NWORK, 1024, ldsBytes, stream>>>(
      W_attn, U_attn, v_attn, W_ih, W_hh, ex, outb, h_final, Wbt, b_out, logits, progress);
}

// Round 17
// 647.117 us; speedup vs baseline: 1.3942x; 1.3942x over previous
//
#include <hip/hip_runtime.h>
#include <hip/hip_fp16.h>
#include <hip/hip_bf16.h>
#include <cstdint>

#define TLEN  256
#define HD    128
#define BATCH 8
#define VOCAB 32000
#define EMBD  32
#define ROWB  272   // 256B row + 16B pad

typedef __attribute__((ext_vector_type(8))) short short8v;
typedef __attribute__((ext_vector_type(8))) unsigned short ushort8v;
typedef __attribute__((ext_vector_type(4))) float f32x4;
typedef __attribute__((ext_vector_type(2))) float f32x2;
typedef __attribute__((ext_vector_type(2))) _Float16 hv2;

__device__ __forceinline__ float tanhfast(float x){
  float e = __builtin_amdgcn_exp2f(x * 2.8853900817779268f);
  return 1.0f - 2.0f * __builtin_amdgcn_rcpf(e + 1.0f);
}
__device__ __forceinline__ unsigned short f2bf(float f){
  unsigned u = __float_as_uint(f);
  return (unsigned short)((u + 0x7fffu + ((u >> 16) & 1u)) >> 16);
}
__device__ __forceinline__ float h2f(unsigned short u){
  return __half2float(__ushort_as_half(u));
}
__device__ __forceinline__ unsigned short f2h(float f){
  return __half_as_ushort(__float2half(f));
}
__device__ __forceinline__ unsigned pk2(float lo, float hi){
  return __builtin_bit_cast(unsigned, __floats2half2_rn(lo, hi));
}
__device__ __forceinline__ float fdot2u(unsigned a, unsigned b, float c){
#if __has_builtin(__builtin_amdgcn_fdot2)
  return __builtin_amdgcn_fdot2(__builtin_bit_cast(hv2, a), __builtin_bit_cast(hv2, b), c, false);
#else
  float2 fa = __half22float2(__builtin_bit_cast(__half2, a));
  float2 fb = __half22float2(__builtin_bit_cast(__half2, b));
  return c + fa.x*fb.x + fa.y*fb.y;
#endif
}
__device__ __forceinline__ f32x2 fma2(f32x2 a, f32x2 b, f32x2 c){
#if __has_builtin(__builtin_elementwise_fma)
  return __builtin_elementwise_fma(a, b, c);
#else
  f32x2 r; r.x = fmaf(a.x, b.x, c.x); r.y = fmaf(a.y, b.y, c.y); return r;
#endif
}
__device__ __forceinline__ void ld8u(const void* p, unsigned* d){
  uint4 a = *(const uint4*)p;
  uint4 b = *(const uint4*)((const char*)p + 16);
  d[0]=a.x; d[1]=a.y; d[2]=a.z; d[3]=a.w; d[4]=b.x; d[5]=b.y; d[6]=b.z; d[7]=b.w;
}
__device__ __forceinline__ void gload_lds16(const void* g, void* l){
  __builtin_amdgcn_global_load_lds((const __attribute__((address_space(1))) void*)g,
                                   (__attribute__((address_space(3))) void*)l, 16, 0, 0);
}

// ---- cross-lane adds ----
__device__ __forceinline__ float dpp_add1(float x){
  int y = __builtin_amdgcn_mov_dpp(__float_as_int(x), 0xB1, 0xF, 0xF, true);
  return x + __int_as_float(y);
}
__device__ __forceinline__ float dpp_add2(float x){
  int y = __builtin_amdgcn_mov_dpp(__float_as_int(x), 0x4E, 0xF, 0xF, true);
  return x + __int_as_float(y);
}
__device__ __forceinline__ float dpp_shl4(float x){   // valid (l&15)<12
  int y = __builtin_amdgcn_mov_dpp(__float_as_int(x), 0x104, 0xF, 0xF, true);
  return x + __int_as_float(y);
}
__device__ __forceinline__ float dpp_shl8(float x){   // valid (l&15)<8
  int y = __builtin_amdgcn_mov_dpp(__float_as_int(x), 0x108, 0xF, 0xF, true);
  return x + __int_as_float(y);
}
__device__ __forceinline__ float swz_add4(float x){
  int y = __builtin_amdgcn_ds_swizzle(__float_as_int(x), 0x101F);
  return x + __int_as_float(y);
}
__device__ __forceinline__ float swz_add16(float x){
  int y = __builtin_amdgcn_ds_swizzle(__float_as_int(x), 0x401F);
  return x + __int_as_float(y);
}

// interleaved score slot: stripe-contiguous for P3
#define SCR(s) ((((s) & 15) << 4) | ((s) >> 4))

// ---------------- merged prep: blocks 0..1023 -> ex ; 1024..5023 -> Wbt ----------------
__global__ void prep_kernel(const int* __restrict__ x, const float* __restrict__ emb,
                            const float* __restrict__ W_ih, const float* __restrict__ b_ih,
                            const float* __restrict__ b_hh, float* __restrict__ ex,
                            const float* __restrict__ W_out, unsigned short* __restrict__ Wbt){
  __shared__ float tile[32][33];
  const int blk = blockIdx.x, tid = threadIdx.x;
  if (blk < 1024){
    // ex[b,t,c] = emb[x[b,t]] @ W_ih[0:32] + b_ih + b_hh  (2 bt per block)
    int bt = blk*2 + (tid >> 7);
    int c  = tid & 127;
    int ix = x[bt];
    const float* er = emb + (long)ix * EMBD;
    float acc = b_ih[c] + b_hh[c];
    #pragma unroll
    for (int e = 0; e < EMBD; ++e) acc += er[e] * W_ih[e * HD + c];
    ex[bt * HD + c] = acc;
  } else {
    // Wbt[n][k] = bf16(W_out[k][n])
    int wid = blk - 1024;                   // 0..3999
    int n0 = (wid % 1000) * 32, k0 = (wid / 1000) * 32;
    int tx = tid & 31, ty = tid >> 5;
    #pragma unroll
    for (int j = 0; j < 4; ++j){
      int k = ty + j * 8;
      tile[k][tx] = W_out[(long)(k0 + k) * VOCAB + n0 + tx];
    }
    __syncthreads();
    #pragma unroll
    for (int j = 0; j < 4; ++j){
      int n = ty + j * 8;
      Wbt[(long)(n0 + n) * HD + k0 + tx] = f2bf(tile[tx][n]);
    }
  }
}

// ---------------- scan (r13, unchanged) ----------------
__launch_bounds__(1024)
__global__ void scan_kernel(const float* __restrict__ W_attn, const float* __restrict__ U_attn,
                            const float* __restrict__ v_attn, const float* __restrict__ W_ih,
                            const float* __restrict__ W_hh, const float* __restrict__ ex,
                            unsigned short* __restrict__ out_bf, float* __restrict__ h_final){
  extern __shared__ char lds[];
  char* keysB = lds;                       // 256*272 = 69632 B (G = e^{2k}, fp16)
  char* hWcB  = lds + 69632;               // 69632 B (h@Wc, fp16) -- zero-backed
  float* fbuf   = (float*)(lds + 139264);
  float* E_pad    = fbuf;                  // 160: e^{2q}
  float* hh_lds   = fbuf + 160;            // 128
  float* scores_e = fbuf + 288;            // 256 (interleaved SCR layout, zero-backed)
  unsigned* h_pk  = (unsigned*)(fbuf + 544); // 64

  const int b    = blockIdx.x;
  const int tid  = threadIdx.x;
  const int lane = tid & 63, wv = tid >> 6;
  const int c_   = tid >> 3, rg = tid & 7;
  const int sg   = lane >> 3, cg = lane & 7;
  const int cg3  = cg & 3;
  const int sgx  = sg + 8*(cg >> 2);            // 0..15 stripe (P3)
  const int cp   = wv*4 + cg3;                  // col pair -> cols 2cp,2cp+1

  const float LOG2E = 1.4426950408889634f;
  const float C2F   = 2.8853900817779268f;

  if (tid < HD) hh_lds[tid] = 0.f;

  // ---- stage weights into packed-fp16 VGPRs ----
  unsigned Wa2[8], Ua2[8], Wh2[8], Wc2[8];
  {
    float* stage = (float*)lds;
    float4* d4 = (float4*)stage;
    {
      const float4* s4 = (const float4*)W_attn;
      for (int i = 0; i < 4; ++i) d4[tid + i*1024] = s4[tid + i*1024];
      __syncthreads();
      #pragma unroll
      for (int i = 0; i < 8; ++i)
        Wa2[i] = pk2(stage[(rg*16 + 2*i)*HD + c_], stage[(rg*16 + 2*i + 1)*HD + c_]);
      __syncthreads();
    }
    {
      const float4* s4 = (const float4*)U_attn;
      for (int i = 0; i < 4; ++i) d4[tid + i*1024] = s4[tid + i*1024];
      __syncthreads();
      #pragma unroll
      for (int i = 0; i < 8; ++i)
        Ua2[i] = pk2(stage[(rg*16 + 2*i)*HD + c_], stage[(rg*16 + 2*i + 1)*HD + c_]);
      __syncthreads();
    }
    {
      const float4* s4 = (const float4*)W_hh;
      for (int i = 0; i < 4; ++i) d4[tid + i*1024] = s4[tid + i*1024];
      __syncthreads();
      #pragma unroll
      for (int i = 0; i < 8; ++i)
        Wh2[i] = pk2(stage[(rg*16 + 2*i)*HD + c_], stage[(rg*16 + 2*i + 1)*HD + c_]);
      __syncthreads();
    }
    {
      const float4* s4 = (const float4*)(W_ih + EMBD*HD);
      for (int i = 0; i < 4; ++i) d4[tid + i*1024] = s4[tid + i*1024];
      __syncthreads();
      #pragma unroll
      for (int i = 0; i < 8; ++i)
        Wc2[i] = pk2(stage[(rg*16 + 2*i)*HD + c_], stage[(rg*16 + 2*i + 1)*HD + c_]);
      __syncthreads();
    }
  }

  // ---- zero-back hWcB + scores_e + h_pk ----
  {
    float4 z = {0.f, 0.f, 0.f, 0.f};
    float4* hz = (float4*)hWcB;
    hz[tid] = z; hz[tid + 1024] = z; hz[tid + 2048] = z; hz[tid + 3072] = z;
    if (tid < 256) hz[tid + 4096] = z;
    if (tid < 64) ((float4*)scores_e)[tid] = z;
    if (tid < 64) h_pk[tid] = 0u;
  }

  // ---- v in registers (cols cg*16..+15) as f32x2 + FULL 128-sum ----
  f32x2 v2[8]; float VsumL;
  {
    const float* vg = v_attn + cg*16;
    float s = 0.f;
    #pragma unroll
    for (int i = 0; i < 8; ++i){
      f32x2 vv; vv.x = vg[2*i]; vv.y = vg[2*i+1];
      v2[i] = vv; s += vv.x + vv.y;
    }
    s = dpp_add1(s); s = dpp_add2(s); s = swz_add4(s);
    VsumL = s * LOG2E;
  }

  const float* exb = ex + (long)b * TLEN * HD;

  for (int t = 0; t < TLEN; ++t){
    float2 evpre = *(const float2*)(exb + t*HD + 2*cp);   // prefetch for P3 tail

    if (t > 0){
      // ---- P1: 4 packed GEMVs of h ----
      {
        unsigned h2u[8];
        ld8u((const char*)h_pk + rg*32, h2u);
        float aq = 0.f, ak = 0.f, ah = 0.f, aw = 0.f;
        #pragma unroll
        for (int i = 0; i < 8; ++i){
          aq = fdot2u(h2u[i], Wa2[i], aq);
          ak = fdot2u(h2u[i], Ua2[i], ak);
          ah = fdot2u(h2u[i], Wh2[i], ah);
          aw = fdot2u(h2u[i], Wc2[i], aw);
        }
        aq = dpp_add1(aq); aq = dpp_add2(aq); aq = dpp_shl4(aq);
        ak = dpp_add1(ak); ak = dpp_add2(ak); ak = dpp_shl4(ak);
        ah = dpp_add1(ah); ah = dpp_add2(ah); ah = dpp_shl4(ah);
        aw = dpp_add1(aw); aw = dpp_add2(aw); aw = dpp_shl4(aw);
        if (rg == 0){
          E_pad[c_ + (c_>>4)*4] = __builtin_amdgcn_exp2f(aq * C2F);      // e^{2q}
          hh_lds[c_] = ah;
          int s = t - 1;
          float G = fminf(__builtin_amdgcn_exp2f(ak * C2F), 60000.f);    // e^{2k}
          *(unsigned short*)(keysB + s*ROWB + c_*2) = f2h(G);
          *(unsigned short*)(hWcB  + s*ROWB + c_*2) = f2h(aw);
        }
      }
      __syncthreads();  // S1

      // ---- P2: e_s = exp(v . tanh(q+k_s)); tanh = 1 - 2/(1+E*G) ----
      {
        f32x2 E2[8];
        {
          const float4* E4 = (const float4*)(E_pad + cg*20);
          #pragma unroll
          for (int i = 0; i < 4; ++i){
            float4 ev = E4[i];
            f32x2 a, bb; a.x = ev.x; a.y = ev.y; bb.x = ev.z; bb.y = ev.w;
            E2[2*i] = a; E2[2*i+1] = bb;
          }
        }
        #pragma unroll
        for (int it = 0; it < 2; ++it){
          int s = wv*8 + sg + it*128;
          if (s < t){
            unsigned gu[8];
            ld8u(keysB + s*ROWB + cg*32, gu);
            f32x2 D[8];
            #pragma unroll
            for (int i = 0; i < 8; ++i){
              hv2 g = __builtin_bit_cast(hv2, gu[i]);
              f32x2 d;
              d.x = fmaf((float)g.x, E2[i].x, 1.0f);
              d.y = fmaf((float)g.y, E2[i].y, 1.0f);
              D[i] = d;
            }
            f32x2 acc2; acc2.x = 0.f; acc2.y = 0.f;
            #pragma unroll
            for (int i = 0; i < 8; i += 2){
              f32x2 p = D[i] * D[i+1];
              float R = __builtin_amdgcn_rcpf(p.x * p.y);
              f32x2 sw = p.yx * R;
              acc2 = fma2(v2[i],   sw * D[i+1], acc2);
              acc2 = fma2(v2[i+1], sw * D[i],   acc2);
            }
            float ac = acc2.x + acc2.y;
            ac = dpp_add1(ac); ac = dpp_add2(ac); ac = dpp_shl4(ac);   // cg-reduce
            float e = __builtin_amdgcn_exp2f(fmaf(-C2F, ac, VsumL));
            if (cg == 0) scores_e[SCR(s)] = e;
          }
        }
      }
      __syncthreads();  // S2
    }

    // ---- P3: ctxWc = (sum_s e_s * hWc[s]) / (sum_s e_s), then h_new inline ----
    {
      float a0 = 0.f, a1 = 0.f, es = 0.f;
      const char* pw = hWcB + cp*4 + sgx*ROWB;
      const float* sc = scores_e + sgx*16;
      int jmax = (t - sgx + 15) >> 4;                  // #valid stripe slots (<=16)
      for (int j = 0; j < jmax; j += 4){
        float4 e4 = *(const float4*)(sc + j);          // 4 scores, zero-backed
        hv2 h0 = __builtin_bit_cast(hv2, *(const unsigned*)(pw));
        hv2 h1 = __builtin_bit_cast(hv2, *(const unsigned*)(pw + 16*ROWB));
        hv2 h2v = __builtin_bit_cast(hv2, *(const unsigned*)(pw + 32*ROWB));
        hv2 h3 = __builtin_bit_cast(hv2, *(const unsigned*)(pw + 48*ROWB));
        es += (e4.x + e4.y) + (e4.z + e4.w);
        a0 = fmaf((float)h0.x, e4.x, a0); a1 = fmaf((float)h0.y, e4.x, a1);
        a0 = fmaf((float)h1.x, e4.y, a0); a1 = fmaf((float)h1.y, e4.y, a1);
        a0 = fmaf((float)h2v.x, e4.z, a0); a1 = fmaf((float)h2v.y, e4.z, a1);
        a0 = fmaf((float)h3.x, e4.w, a0); a1 = fmaf((float)h3.y, e4.w, a1);
        pw += 64*ROWB;
      }
      a0 = dpp_shl4(a0); a0 = dpp_shl8(a0); a0 = swz_add16(a0); a0 += __shfl_xor(a0, 32);
      a1 = dpp_shl4(a1); a1 = dpp_shl8(a1); a1 = swz_add16(a1); a1 += __shfl_xor(a1, 32);
      es = dpp_shl4(es); es = dpp_shl8(es); es = swz_add16(es); es += __shfl_xor(es, 32);
      if (sgx == 0){
        float invZ = __builtin_amdgcn_rcpf(es);        // es>0 for t>0; t=0 selected away
        float cw0 = (t > 0) ? a0 * invZ : 0.f;
        float cw1 = (t > 0) ? a1 * invZ : 0.f;
        int c0 = 2*cp;
        float2 hhv = *(const float2*)(&hh_lds[c0]);
        float h0 = tanhfast(evpre.x + hhv.x + cw0);
        float h1 = tanhfast(evpre.y + hhv.y + cw1);
        h_pk[cp] = pk2(h0, h1);
        unsigned po = (unsigned)f2bf(h0) | ((unsigned)f2bf(h1) << 16);
        *(unsigned*)(&out_bf[((long)b*TLEN + t)*HD + c0]) = po;
        if (t == TLEN-1){ float2 hw = { h0, h1 }; *(float2*)&h_final[b*HD + c0] = hw; }
      }
    }
    __syncthreads();  // S3
  }
}

// ---------------- logits GEMM (r13, unchanged) ----------------
__launch_bounds__(256, 2)
__global__ void gemm_kernel(const unsigned short* __restrict__ A, const unsigned short* __restrict__ Bt,
                            const float* __restrict__ bias, float* __restrict__ C){
  __shared__ char sAB[65536];
  char* sA = sAB;
  char* sB = sAB + 32768;
  const int tid = threadIdx.x;
  const int lane = tid & 63, wv = tid >> 6;
  const int n0 = blockIdx.x * 128, m0 = blockIdx.y * 128;
  const char* Ab = (const char*)A + (long)m0 * 256;
  const char* Bb = (const char*)Bt + (long)n0 * 256;

  #pragma unroll
  for (int it = 0; it < 8; ++it){
    int p  = it*4096 + wv*1024 + lane*16;
    int ps = p ^ (((p >> 8) & 7) << 4);
    gload_lds16(Ab + ps, sA + it*4096 + wv*1024);
    gload_lds16(Bb + ps, sB + it*4096 + wv*1024);
  }
  __syncthreads();

  f32x4 acc[2][8] = {};
  const int r15 = lane & 15, r4 = lane >> 4;
  #pragma unroll
  for (int kk = 0; kk < 4; ++kk){
    short8v af[2], bfr[8];
    #pragma unroll
    for (int mi = 0; mi < 2; ++mi){
      int row = wv*32 + mi*16 + r15;
      int off = row*256 + kk*64 + r4*16;
      af[mi] = *(const short8v*)(sA + (off ^ ((row & 7) << 4)));
    }
    #pragma unroll
    for (int ni = 0; ni < 8; ++ni){
      int row = ni*16 + r15;
      int off = row*256 + kk*64 + r4*16;
      bfr[ni] = *(const short8v*)(sB + (off ^ ((row & 7) << 4)));
    }
    #pragma unroll
    for (int ni = 0; ni < 8; ++ni)
      #pragma unroll
      for (int mi = 0; mi < 2; ++mi)
        acc[mi][ni] = __builtin_amdgcn_mfma_f32_16x16x32_bf16(af[mi], bfr[ni], acc[mi][ni], 0, 0, 0);
  }

  #pragma unroll
  for (int mi = 0; mi < 2; ++mi){
    int rbase = m0 + wv*32 + mi*16 + r4*4;
    #pragma unroll
    for (int ni = 0; ni < 8; ++ni){
      int col = n0 + ni*16 + r15;
      float bv = bias[col];
      #pragma unroll
      for (int j = 0; j < 4; ++j)
        C[(long)(rbase + j) * VOCAB + col] = acc[mi][ni][j] + bv;
    }
  }
}

extern "C" void kernel_launch(void* const* d_in, const int* in_sizes, int n_in,
                              void* d_out, int out_size, void* d_ws, size_t ws_size,
                              hipStream_t stream){
  const int*   x      = (const int*)d_in[0];
  const float* emb    = (const float*)d_in[1];
  const float* W_attn = (const float*)d_in[2];
  const float* U_attn = (const float*)d_in[3];
  const float* v_attn = (const float*)d_in[4];
  const float* W_ih   = (const float*)d_in[5];
  const float* b_ih   = (const float*)d_in[6];
  const float* W_hh   = (const float*)d_in[7];
  const float* b_hh   = (const float*)d_in[8];
  const float* W_out  = (const float*)d_in[9];
  const float* b_out  = (const float*)d_in[10];

  float* logits  = (float*)d_out;
  float* h_final = logits + (long)BATCH * TLEN * VOCAB;

  char* ws = (char*)d_ws;
  float*          ex   = (float*)ws;                                // 1 MB
  unsigned short* Wbt  = (unsigned short*)(ws + 1048576);           // 8.192 MB
  unsigned short* outb = (unsigned short*)(ws + 1048576 + 8192000); // 0.5 MB

  prep_kernel<<<1024 + 4000, 256, 0, stream>>>(x, emb, W_ih, b_ih, b_hh, ex, W_out, Wbt);

  const int ldsBytes = 139264 + 608*4;   // 141,696 B
  hipFuncSetAttribute((const void*)scan_kernel, hipFuncAttributeMaxDynamicSharedMemorySize, ldsBytes);
  scan_kernel<<<BATCH, 1024, ldsBytes, stream>>>(W_attn, U_attn, v_attn, W_ih, W_hh, ex, outb, h_final);

  gemm_kernel<<<dim3(VOCAB/128, (BATCH*TLEN)/128), 256, 0, stream>>>(outb, Wbt, b_out, logits);
}